// Round 5
// baseline (52.229 us; speedup 1.0000x reference)
//
#include <hip/hip_runtime.h>

// LIF forward: u_t = u + (ir_t - u)/10 ; o_t = 1[u_t >= 1] ; u_rest=0 -> no reset.
// R5: out stores via inline asm `global_store_dwordx4 ... sc1 nt` — write-through
// past L2 (sc1) + non-temporal MALL hint (nt), so the 105 MB write stream stops
// evicting the 105 MB `ir` slab from the 256 MiB L3 across graph replays.
// If ir goes fully L3-resident, floor = write-only ~105 MB @ ~7 TB/s ~= 15-17 us.
// Exact IEEE f32 divide by 10.0f -> bitwise-identical to numpy ref (absmax 0.0).

#define T_STEPS 100
#define BN      262144        // B*N = 32*8192
#define VEC     4
#define NTHR    (BN / VEC)    // 65536 threads

typedef float f32x4 __attribute__((ext_vector_type(4)));

__global__ __launch_bounds__(256) void lif_fwd(const f32x4* __restrict__ ir,
                                               const f32x4* __restrict__ u0,
                                               f32x4* __restrict__ out) {
    const int idx = blockIdx.x * blockDim.x + threadIdx.x;   // 0..NTHR-1
    const int stride = BN / VEC;                             // f32x4 per time slab

    f32x4 u = u0[idx];

    #pragma unroll 10
    for (int t = 0; t < T_STEPS; ++t) {
        const f32x4 ir_t = ir[(size_t)t * stride + idx];

        // Bitwise-match reference: u + (-(u-0) + ir)/10 == u + (ir-u)/10.0f
        // (IEEE f32 division, no mul -> no FMA contraction hazard)
        f32x4 o;
        #pragma unroll
        for (int j = 0; j < VEC; ++j) {
            u[j] = u[j] + (ir_t[j] - u[j]) / 10.0f;
            o[j] = ((u[j] - 1.0f) >= 0.0f) ? 1.0f : 0.0f;
        }

        // Streaming store: bypass L2 (sc1, write-through) + non-temporal (nt)
        // so out-writes don't allocate/evict in MALL; keeps ir L3-resident.
        f32x4* p = &out[(size_t)t * stride + idx];
        asm volatile("global_store_dwordx4 %0, %1, off sc1 nt"
                     :: "v"(p), "v"(o) : "memory");
        // u_next = u_t + u_rest * o_t = u_t  (u_rest == 0)
    }

    // Drain posted writes before s_endpgm (compiler can't see asm stores).
    asm volatile("s_waitcnt vmcnt(0)" ::: "memory");
}

extern "C" void kernel_launch(void* const* d_in, const int* in_sizes, int n_in,
                              void* d_out, int out_size, void* d_ws, size_t ws_size,
                              hipStream_t stream) {
    const f32x4* ir = (const f32x4*)d_in[0];   // [T, B, N] f32
    const f32x4* u0 = (const f32x4*)d_in[1];   // [B, N] f32
    f32x4* out = (f32x4*)d_out;                // [T, B, N] f32

    lif_fwd<<<dim3(NTHR / 256), dim3(256), 0, stream>>>(ir, u0, out);
}

// Round 6
// 31.852 us; speedup vs baseline: 1.6397x; 1.6397x over previous
//
#include <hip/hip_runtime.h>

// LIF forward: u_t = u + (ir_t - u)/10 ; o_t = 1[u_t >= 1] ; u_rest=0 -> no reset.
// R6: A/B on the store path — R4 (31.1 us) used __builtin_nontemporal_store;
// this is identical except PLAIN vectorized stores (L2 write-back allocation).
// R5 taught: sc1/nt can't control the memory-side MALL; FETCH_SIZE ~52 MB is
// structural (210 MB working set vs 256 MB MALL). Single-variable A/B to close
// out the store-path question before declaring roofline.
// Exact IEEE f32 divide by 10.0f -> bitwise-identical to numpy ref (absmax 0.0).
// Spike test u >= 1.0f == (u-1)>=0 exactly (Sterbenz on [0.5,2]; sign-exact
// elsewhere) — one fewer VALU op, zero numerics change.

#define T_STEPS 100
#define BN      262144        // B*N = 32*8192
#define VEC     4
#define NTHR    (BN / VEC)    // 65536 threads

typedef float f32x4 __attribute__((ext_vector_type(4)));

__global__ __launch_bounds__(256) void lif_fwd(const f32x4* __restrict__ ir,
                                               const f32x4* __restrict__ u0,
                                               f32x4* __restrict__ out) {
    const int idx = blockIdx.x * blockDim.x + threadIdx.x;   // 0..NTHR-1
    const int stride = BN / VEC;                             // f32x4 per time slab

    f32x4 u = u0[idx];

    #pragma unroll 10
    for (int t = 0; t < T_STEPS; ++t) {
        const f32x4 ir_t = ir[(size_t)t * stride + idx];

        // Bitwise-match reference: u + (-(u-0) + ir)/10 == u + (ir-u)/10.0f
        // (IEEE f32 division, no mul -> no FMA contraction hazard)
        f32x4 o;
        #pragma unroll
        for (int j = 0; j < VEC; ++j) {
            u[j] = u[j] + (ir_t[j] - u[j]) / 10.0f;
            o[j] = (u[j] >= 1.0f) ? 1.0f : 0.0f;
        }
        out[(size_t)t * stride + idx] = o;   // plain store (A/B vs R4's NT)
        // u_next = u_t + u_rest * o_t = u_t  (u_rest == 0)
    }
}

extern "C" void kernel_launch(void* const* d_in, const int* in_sizes, int n_in,
                              void* d_out, int out_size, void* d_ws, size_t ws_size,
                              hipStream_t stream) {
    const f32x4* ir = (const f32x4*)d_in[0];   // [T, B, N] f32
    const f32x4* u0 = (const f32x4*)d_in[1];   // [B, N] f32
    f32x4* out = (f32x4*)d_out;                // [T, B, N] f32

    lif_fwd<<<dim3(NTHR / 256), dim3(256), 0, stream>>>(ir, u0, out);
}